// Round 1
// baseline (149.118 us; speedup 1.0000x reference)
//
#include <hip/hip_runtime.h>
#include <math.h>

#define NPIX   614400   // 8*240*320
#define HW     76800
#define NBATCH 8
#define NB     256
#define NEDGE  257

// ws layout:
//   [0,48):       double sums[6]: {cnt, sumsq, sumd, sumd2, dir2sum, pad}
//   [48,52):      uint  detect count (nonzero bytes in first NPIX bytes of mask)
//   [64,64+8192): uint  cmin[NBATCH*NB]  (float bits, monotone for d2>=0)

__device__ __forceinline__ double wsum64(double v) {
#pragma unroll
  for (int o = 32; o > 0; o >>= 1) v += __shfl_down(v, o, 64);
  return v;
}

__global__ void k_detect(const unsigned char* __restrict__ m,
                         unsigned int* __restrict__ dcnt) {
  unsigned int c = 0;
  for (int i = blockIdx.x * blockDim.x + threadIdx.x; i < NPIX;
       i += gridDim.x * blockDim.x)
    c += (m[i] != 0u) ? 1u : 0u;
#pragma unroll
  for (int o = 32; o > 0; o >>= 1) c += __shfl_down(c, o, 64);
  __shared__ unsigned int sh[4];
  int lane = threadIdx.x & 63, wid = threadIdx.x >> 6;
  if (lane == 0) sh[wid] = c;
  __syncthreads();
  if (threadIdx.x == 0) atomicAdd(dcnt, sh[0] + sh[1] + sh[2] + sh[3]);
}

__global__ void k_masked(const float* __restrict__ p, const float* __restrict__ t,
                         const void* __restrict__ mask,
                         const unsigned int* __restrict__ dcnt,
                         double* __restrict__ sums) {
  const bool bytemode = (*dcnt > (NPIX / 4));  // bool(1B) vs int32 storage
  int i = blockIdx.x * blockDim.x + threadIdx.x;
  double cnt = 0, ssq = 0, sd = 0, sd2 = 0;
  if (i < NPIX) {
    bool mv = bytemode ? (((const unsigned char*)mask)[i] != 0)
                       : (((const int*)mask)[i] != 0);
    if (mv) {
      float pi = p[i], ti = t[i];
      float diff = pi - ti;
      float d = logf(pi + 1e-10f) - logf(ti + 1e-10f);
      cnt = 1.0;
      ssq = (double)diff * (double)diff;
      sd  = (double)d;
      sd2 = (double)d * (double)d;
    }
  }
  cnt = wsum64(cnt); ssq = wsum64(ssq); sd = wsum64(sd); sd2 = wsum64(sd2);
  __shared__ double sh[4][4];
  int lane = threadIdx.x & 63, wid = threadIdx.x >> 6;
  if (lane == 0) { sh[wid][0] = cnt; sh[wid][1] = ssq; sh[wid][2] = sd; sh[wid][3] = sd2; }
  __syncthreads();
  if (threadIdx.x < 4) {
    double v = sh[0][threadIdx.x] + sh[1][threadIdx.x] + sh[2][threadIdx.x] + sh[3][threadIdx.x];
    atomicAdd(&sums[threadIdx.x], v);
  }
}

__global__ void k_chamfer(const float* __restrict__ target,
                          const float* __restrict__ edges,
                          double* __restrict__ dir2sum,
                          unsigned int* __restrict__ gcmin) {
  __shared__ float c_lds[NB];
  __shared__ float t_lds[NB];
  __shared__ double sh[4];
  const int b = blockIdx.y;
  const int tid = threadIdx.x;
  c_lds[tid] = 0.5f * (edges[b * NEDGE + tid] + edges[b * NEDGE + tid + 1]);
  const float tv = target[b * HW + blockIdx.x * NB + tid];
  t_lds[tid] = tv;
  __syncthreads();

  // pass A (dir2): this thread's target vs all centers
  float tmin = 1e30f;
#pragma unroll 8
  for (int j = 0; j < NB; ++j) {
    float d = tv - c_lds[j];
    tmin = fminf(tmin, d * d);
  }
  // pass B (dir1): this thread's center vs this block's targets
  const float cv = c_lds[tid];
  float cmin = 1e30f;
#pragma unroll 8
  for (int i = 0; i < NB; ++i) {
    float d = cv - t_lds[i];
    cmin = fminf(cmin, d * d);
  }
  atomicMin(&gcmin[b * NB + tid], __float_as_uint(cmin));

  double s = wsum64((double)tmin);
  int lane = tid & 63, wid = tid >> 6;
  if (lane == 0) sh[wid] = s;
  __syncthreads();
  if (tid == 0) atomicAdd(dir2sum, sh[0] + sh[1] + sh[2] + sh[3]);
}

__global__ void k_final(const double* __restrict__ sums,
                        const unsigned int* __restrict__ gcmin,
                        float* __restrict__ out) {
  double part = 0;
  for (int i = threadIdx.x; i < NBATCH * NB; i += 256)
    part += (double)__uint_as_float(gcmin[i]);
  part = wsum64(part);
  __shared__ double sh[4];
  int lane = threadIdx.x & 63, wid = threadIdx.x >> 6;
  if (lane == 0) sh[wid] = part;
  __syncthreads();
  if (threadIdx.x == 0) {
    double dir1 = sh[0] + sh[1] + sh[2] + sh[3];
    double cnt = sums[0], ssq = sums[1], sd = sums[2], sd2 = sums[3], dir2 = sums[4];
    double l2 = sqrt(ssq / cnt);
    double dm = sd / cnt, d2m = sd2 / cnt;
    double silog = 10.0 * sqrt(d2m - 0.85 * dm * dm);
    double chamfer = (dir1 + dir2) / (double)NBATCH;
    out[0] = (float)(l2 + silog + chamfer);
  }
}

extern "C" void kernel_launch(void* const* d_in, const int* in_sizes, int n_in,
                              void* d_out, int out_size, void* d_ws, size_t ws_size,
                              hipStream_t stream) {
  const float* pred  = (const float*)d_in[0];
  const float* targ  = (const float*)d_in[1];
  const float* edges = (const float*)d_in[2];
  const void*  mask  = d_in[3];

  char* ws = (char*)d_ws;
  double* sums = (double*)ws;                       // 6 doubles
  unsigned int* dcnt  = (unsigned int*)(ws + 48);
  unsigned int* gcmin = (unsigned int*)(ws + 64);   // 2048 uints

  hipMemsetAsync(ws, 0, 64, stream);
  hipMemsetAsync(ws + 64, 0xFF, NBATCH * NB * 4, stream);

  k_detect<<<256, 256, 0, stream>>>((const unsigned char*)mask, dcnt);
  k_masked<<<NPIX / 256, 256, 0, stream>>>(pred, targ, mask, dcnt, sums);
  k_chamfer<<<dim3(HW / NB, NBATCH), NB, 0, stream>>>(targ, edges, sums + 4, gcmin);
  k_final<<<1, 256, 0, stream>>>(sums, gcmin, (float*)d_out);
}

// Round 2
// 39.214 us; speedup vs baseline: 3.8027x; 3.8027x over previous
//
#include <hip/hip_runtime.h>
#include <math.h>

#define NPIX   614400   // 8*240*320
#define HW     76800
#define NBATCH 8
#define NB     256
#define NEDGE  257
#define ELEMS  4
#define MAIN_BLOCKS (NPIX / (256 * ELEMS))     // 600
#define BPB (MAIN_BLOCKS / NBATCH)             // 75 blocks per batch
#define DET_BYTES 16384

// ws layout:
//   [0,40)        double sums[5]: {cnt, sumsq, sumd, sumd2, dir2}
//   [48,52)       uint flag: 1 = mask stored as bytes, 0 = int32
//   [64,8256)     float cs[8][256]   sorted bin centers
//   [8256,16448)  uint  gD[8][256]   per-center bracket min |t-c| (float bits)

__device__ __forceinline__ double wsum64(double v) {
#pragma unroll
  for (int o = 32; o > 0; o >>= 1) v += __shfl_down(v, o, 64);
  return v;
}

__global__ void k_prep(const float* __restrict__ edges,
                       const unsigned char* __restrict__ mask,
                       double* __restrict__ sums,
                       unsigned int* __restrict__ flag,
                       float* __restrict__ cs,
                       unsigned int* __restrict__ gD) {
  const int tid = threadIdx.x;
  const int b = blockIdx.x;
  if (b < NBATCH) {
    // bitonic-sort this batch's 256 bin centers in LDS
    __shared__ float s[NB];
    s[tid] = 0.5f * (edges[b * NEDGE + tid] + edges[b * NEDGE + tid + 1]);
    __syncthreads();
    for (int k = 2; k <= NB; k <<= 1) {
      for (int j = k >> 1; j > 0; j >>= 1) {
        int ixj = tid ^ j;
        if (ixj > tid) {
          float a = s[tid], c = s[ixj];
          bool up = ((tid & k) == 0);
          if ((a > c) == up) { s[tid] = c; s[ixj] = a; }
        }
        __syncthreads();
      }
    }
    cs[b * NB + tid] = s[tid];
    gD[b * NB + tid] = 0x7F800000u;  // +inf
  } else {
    // mask dtype detect: bool(1B) ~50% nonzero bytes, int32 ~12.5%
    unsigned int c = 0;
    for (int i = tid; i < DET_BYTES; i += 256) c += (mask[i] != 0) ? 1u : 0u;
#pragma unroll
    for (int o = 32; o > 0; o >>= 1) c += __shfl_down(c, o, 64);
    __shared__ unsigned int sh[4];
    if ((tid & 63) == 0) sh[tid >> 6] = c;
    __syncthreads();
    if (tid == 0) *flag = ((sh[0] + sh[1] + sh[2] + sh[3]) > (DET_BYTES / 4)) ? 1u : 0u;
    if (tid < 5) sums[tid] = 0.0;
  }
}

__global__ void k_main(const float* __restrict__ p, const float* __restrict__ t,
                       const void* __restrict__ mask,
                       const unsigned int* __restrict__ flag,
                       const float* __restrict__ cs,
                       double* __restrict__ sums,
                       unsigned int* __restrict__ gD) {
  __shared__ float c_lds[NB];
  __shared__ unsigned int d_lds[NB];
  __shared__ double shred[4][5];
  const int tid = threadIdx.x;
  const int b = blockIdx.x / BPB;
  const int base = blockIdx.x * (256 * ELEMS) + tid * ELEMS;

  c_lds[tid] = cs[b * NB + tid];
  d_lds[tid] = 0x7F800000u;
  __syncthreads();

  const float4 p4 = *(const float4*)(p + base);
  const float4 t4 = *(const float4*)(t + base);
  float pe[ELEMS] = {p4.x, p4.y, p4.z, p4.w};
  float te[ELEMS] = {t4.x, t4.y, t4.z, t4.w};
  int me[ELEMS];
  if (*flag) {
    uchar4 m4 = *(const uchar4*)((const unsigned char*)mask + base);
    me[0] = m4.x; me[1] = m4.y; me[2] = m4.z; me[3] = m4.w;
  } else {
    int4 m4 = *(const int4*)((const int*)mask + base);
    me[0] = m4.x; me[1] = m4.y; me[2] = m4.z; me[3] = m4.w;
  }

  double cnt = 0, ssq = 0, sd = 0, sd2 = 0, dir2 = 0;
#pragma unroll
  for (int e = 0; e < ELEMS; ++e) {
    const float pi = pe[e], ti = te[e];
    if (me[e]) {
      float diff = pi - ti;
      float d = logf(pi + 1e-10f) - logf(ti + 1e-10f);
      cnt += 1.0;
      ssq += (double)diff * (double)diff;
      sd  += (double)d;
      sd2 += (double)d * (double)d;
    }
    // binary search: largest k with c[k] <= ti (chamfer uses ALL targets)
    int k = -1;
#pragma unroll
    for (int s = 128; s > 0; s >>= 1) {
      int nk = k + s;
      if (nk < NB && c_lds[nk] <= ti) k = nk;
    }
    float dl = (k >= 0)     ? ti - c_lds[k]     : 1e30f;
    float dr = (k + 1 < NB) ? c_lds[k + 1] - ti : 1e30f;
    if (k >= 0)     atomicMin(&d_lds[k],     __float_as_uint(dl));
    if (k + 1 < NB) atomicMin(&d_lds[k + 1], __float_as_uint(dr));
    float dmin = fminf(dl, dr);
    dir2 += (double)dmin * (double)dmin;
  }

  __syncthreads();
  atomicMin(&gD[b * NB + tid], d_lds[tid]);

  double v[5] = {cnt, ssq, sd, sd2, dir2};
  const int lane = tid & 63, wid = tid >> 6;
#pragma unroll
  for (int i = 0; i < 5; ++i) {
    double r = wsum64(v[i]);
    if (lane == 0) shred[wid][i] = r;
  }
  __syncthreads();
  if (tid < 5) {
    double r = shred[0][tid] + shred[1][tid] + shred[2][tid] + shred[3][tid];
    atomicAdd(&sums[tid], r);
  }
}

__device__ float scan_min(float v, int tid, float* sc, bool forward) {
  sc[tid] = v;
  __syncthreads();
#pragma unroll
  for (int off = 1; off < NB; off <<= 1) {
    int src = forward ? tid - off : tid + off;
    float u = (src >= 0 && src < NB) ? sc[src] : 1e38f;
    __syncthreads();
    sc[tid] = fminf(sc[tid], u);
    __syncthreads();
  }
  float r = sc[tid];
  __syncthreads();
  return r;
}

__global__ void k_final(const double* __restrict__ sums,
                        const float* __restrict__ cs,
                        const unsigned int* __restrict__ gD,
                        float* __restrict__ out) {
  __shared__ float sc[NB];
  __shared__ double shred[4];
  const int tid = threadIdx.x;
  double dir1 = 0.0;
  for (int b = 0; b < NBATCH; ++b) {
    float c = cs[b * NB + tid];
    float D = __uint_as_float(gD[b * NB + tid]);
    // 1-D distance transform: dist_j = min(prefmin(D-c)_j + c_j, sufmin(D+c)_j - c_j)
    float pA = scan_min(D - c, tid, sc, true);
    float sB = scan_min(D + c, tid, sc, false);
    float dist = fminf(pA + c, sB - c);
    dir1 += (double)dist * (double)dist;
  }
  double r = wsum64(dir1);
  const int lane = tid & 63, wid = tid >> 6;
  if (lane == 0) shred[wid] = r;
  __syncthreads();
  if (tid == 0) {
    double d1 = shred[0] + shred[1] + shred[2] + shred[3];
    double cnt = sums[0], ssq = sums[1], sd = sums[2], sd2 = sums[3], d2 = sums[4];
    double l2 = sqrt(ssq / cnt);
    double dm = sd / cnt, d2m = sd2 / cnt;
    double silog = 10.0 * sqrt(d2m - 0.85 * dm * dm);
    double chamfer = (d1 + d2) / (double)NBATCH;
    out[0] = (float)(l2 + silog + chamfer);
  }
}

extern "C" void kernel_launch(void* const* d_in, const int* in_sizes, int n_in,
                              void* d_out, int out_size, void* d_ws, size_t ws_size,
                              hipStream_t stream) {
  const float* pred  = (const float*)d_in[0];
  const float* targ  = (const float*)d_in[1];
  const float* edges = (const float*)d_in[2];
  const void*  mask  = d_in[3];

  char* ws = (char*)d_ws;
  double* sums       = (double*)ws;
  unsigned int* flag = (unsigned int*)(ws + 48);
  float* cs          = (float*)(ws + 64);
  unsigned int* gD   = (unsigned int*)(ws + 8256);

  k_prep<<<NBATCH + 1, NB, 0, stream>>>(edges, (const unsigned char*)mask,
                                        sums, flag, cs, gD);
  k_main<<<MAIN_BLOCKS, NB, 0, stream>>>(pred, targ, mask, flag, cs, sums, gD);
  k_final<<<1, NB, 0, stream>>>(sums, cs, gD, (float*)d_out);
}

// Round 3
// 25.406 us; speedup vs baseline: 5.8695x; 1.5435x over previous
//
#include <hip/hip_runtime.h>
#include <math.h>

#define NPIX   614400   // 8*240*320
#define HW     76800
#define NBATCH 8
#define NB     256
#define NEDGE  257
#define ELEMS  4
#define MAIN_BLOCKS (NPIX / (256 * ELEMS))     // 600
#define BPB (MAIN_BLOCKS / NBATCH)             // 75 blocks per batch
#define DET_BYTES 16384
#define FINF 3.402823466e+38f

// ws layout:
//   [0,40)        double sums[5]: {cnt, sumsq, sumd, sumd2, dir2}
//   [48,52)       uint flag: 1 = mask stored as bytes, 0 = int32
//   [64,8256)     float cs[8][256]   sorted bin centers
//   [8256,16448)  uint  gD[8][256]   per-center bracket min |t-c| (float bits)

__device__ __forceinline__ double wsum64(double v) {
#pragma unroll
  for (int o = 32; o > 0; o >>= 1) v += __shfl_down(v, o, 64);
  return v;
}

__global__ void k_prep(const float* __restrict__ edges,
                       const unsigned char* __restrict__ mask,
                       double* __restrict__ sums,
                       unsigned int* __restrict__ flag,
                       float* __restrict__ cs,
                       unsigned int* __restrict__ gD) {
  const int tid = threadIdx.x;
  const int b = blockIdx.x;
  if (b < NBATCH) {
    // bitonic sort of 256 centers; intra-wave stages use shfl (no barrier)
    __shared__ float s[NB];
    float v = 0.5f * (edges[b * NEDGE + tid] + edges[b * NEDGE + tid + 1]);
    for (int k = 2; k <= NB; k <<= 1) {
      for (int j = k >> 1; j > 0; j >>= 1) {
        float partner;
        if (j < 64) {
          partner = __shfl_xor(v, j, 64);
        } else {
          s[tid] = v;
          __syncthreads();
          partner = s[tid ^ j];
          __syncthreads();
        }
        const bool up = ((tid & k) == 0);
        const bool lowhalf = ((tid & j) == 0);
        v = (lowhalf == up) ? fminf(v, partner) : fmaxf(v, partner);
      }
    }
    cs[b * NB + tid] = v;
    gD[b * NB + tid] = 0x7F800000u;  // +inf
  } else {
    // mask dtype detect: bool(1B) ~50% nonzero bytes, int32 ~12.5%
    unsigned int c = 0;
    for (int i = tid; i < DET_BYTES; i += 256) c += (mask[i] != 0) ? 1u : 0u;
#pragma unroll
    for (int o = 32; o > 0; o >>= 1) c += __shfl_down(c, o, 64);
    __shared__ unsigned int sh[4];
    if ((tid & 63) == 0) sh[tid >> 6] = c;
    __syncthreads();
    if (tid == 0) *flag = ((sh[0] + sh[1] + sh[2] + sh[3]) > (DET_BYTES / 4)) ? 1u : 0u;
    if (tid < 5) sums[tid] = 0.0;
  }
}

__global__ void k_main(const float* __restrict__ p, const float* __restrict__ t,
                       const void* __restrict__ mask,
                       const unsigned int* __restrict__ flag,
                       const float* __restrict__ cs,
                       double* __restrict__ sums,
                       unsigned int* __restrict__ gD) {
  __shared__ float c_lds[NB];
  __shared__ unsigned int d_lds[NB];
  __shared__ double shred[4][5];
  const int tid = threadIdx.x;
  const int b = blockIdx.x / BPB;
  const int base = blockIdx.x * (256 * ELEMS) + tid * ELEMS;

  c_lds[tid] = cs[b * NB + tid];
  d_lds[tid] = 0x7F800000u;
  __syncthreads();

  const float4 p4 = *(const float4*)(p + base);
  const float4 t4 = *(const float4*)(t + base);
  float pe[ELEMS] = {p4.x, p4.y, p4.z, p4.w};
  float te[ELEMS] = {t4.x, t4.y, t4.z, t4.w};
  int me[ELEMS];
  if (*flag) {
    uchar4 m4 = *(const uchar4*)((const unsigned char*)mask + base);
    me[0] = m4.x; me[1] = m4.y; me[2] = m4.z; me[3] = m4.w;
  } else {
    int4 m4 = *(const int4*)((const int*)mask + base);
    me[0] = m4.x; me[1] = m4.y; me[2] = m4.z; me[3] = m4.w;
  }

  double cnt = 0, ssq = 0, sd = 0, sd2 = 0, dir2 = 0;
#pragma unroll
  for (int e = 0; e < ELEMS; ++e) {
    const float pi = pe[e], ti = te[e];
    if (me[e]) {
      float diff = pi - ti;
      float d = logf(pi + 1e-10f) - logf(ti + 1e-10f);
      cnt += 1.0;
      ssq += (double)diff * (double)diff;
      sd  += (double)d;
      sd2 += (double)d * (double)d;
    }
    // binary search: largest k with c[k] <= ti
    int k = -1;
#pragma unroll
    for (int s = 128; s > 0; s >>= 1) {
      int nk = k + s;
      if (nk < NB && c_lds[nk] <= ti) k = nk;
    }
    float dl = (k >= 0)     ? ti - c_lds[k]     : 1e30f;
    float dr = (k + 1 < NB) ? c_lds[k + 1] - ti : 1e30f;
    if (k >= 0)     atomicMin(&d_lds[k],     __float_as_uint(dl));
    if (k + 1 < NB) atomicMin(&d_lds[k + 1], __float_as_uint(dr));
    float dmin = fminf(dl, dr);
    dir2 += (double)dmin * (double)dmin;
  }

  __syncthreads();
  atomicMin(&gD[b * NB + tid], d_lds[tid]);

  double v[5] = {cnt, ssq, sd, sd2, dir2};
  const int lane = tid & 63, wid = tid >> 6;
#pragma unroll
  for (int i = 0; i < 5; ++i) {
    double r = wsum64(v[i]);
    if (lane == 0) shred[wid][i] = r;
  }
  __syncthreads();
  if (tid < 5) {
    double r = shred[0][tid] + shred[1][tid] + shred[2][tid] + shred[3][tid];
    atomicAdd(&sums[tid], r);
  }
}

__global__ void k_final(const double* __restrict__ sums,
                        const float* __restrict__ cs,
                        const unsigned int* __restrict__ gD,
                        float* __restrict__ out) {
  __shared__ double shred[4];
  const int tid = threadIdx.x;
  const int lane = tid & 63, wid = tid >> 6;
  double dir1 = 0.0;

#pragma unroll
  for (int r = 0; r < 2; ++r) {
    const int b = wid + r * 4;
    const float4 c4 = *(const float4*)(cs + b * NB + lane * 4);
    const uint4 d4 = *(const uint4*)(gD + b * NB + lane * 4);
    float c[4] = {c4.x, c4.y, c4.z, c4.w};
    float D[4] = {__uint_as_float(d4.x), __uint_as_float(d4.y),
                  __uint_as_float(d4.z), __uint_as_float(d4.w)};

    // prefix-inclusive min of (D - c) over flat index
    float pa[4];
    pa[0] = D[0] - c[0];
    pa[1] = fminf(pa[0], D[1] - c[1]);
    pa[2] = fminf(pa[1], D[2] - c[2]);
    pa[3] = fminf(pa[2], D[3] - c[3]);
    float s = pa[3];
#pragma unroll
    for (int off = 1; off < 64; off <<= 1) {
      float u = __shfl_up(s, off, 64);
      if (lane >= off) s = fminf(s, u);
    }
    float exL = __shfl_up(s, 1, 64);
    if (lane == 0) exL = FINF;

    // suffix-inclusive min of (D + c)
    float sb[4];
    sb[3] = D[3] + c[3];
    sb[2] = fminf(sb[3], D[2] + c[2]);
    sb[1] = fminf(sb[2], D[1] + c[1]);
    sb[0] = fminf(sb[1], D[0] + c[0]);
    float s2 = sb[0];
#pragma unroll
    for (int off = 1; off < 64; off <<= 1) {
      float u = __shfl_down(s2, off, 64);
      if (lane + off < 64) s2 = fminf(s2, u);
    }
    float exR = __shfl_down(s2, 1, 64);
    if (lane == 63) exR = FINF;

#pragma unroll
    for (int i = 0; i < 4; ++i) {
      float pref = fminf(exL, pa[i]);
      float suf  = fminf(exR, sb[i]);
      float dist = fminf(pref + c[i], suf - c[i]);
      dir1 += (double)dist * (double)dist;
    }
  }

  dir1 = wsum64(dir1);
  if (lane == 0) shred[wid] = dir1;
  __syncthreads();
  if (tid == 0) {
    double d1 = shred[0] + shred[1] + shred[2] + shred[3];
    double cnt = sums[0], ssq = sums[1], sd = sums[2], sd2 = sums[3], d2 = sums[4];
    double l2 = sqrt(ssq / cnt);
    double dm = sd / cnt, d2m = sd2 / cnt;
    double silog = 10.0 * sqrt(d2m - 0.85 * dm * dm);
    double chamfer = (d1 + d2) / (double)NBATCH;
    out[0] = (float)(l2 + silog + chamfer);
  }
}

extern "C" void kernel_launch(void* const* d_in, const int* in_sizes, int n_in,
                              void* d_out, int out_size, void* d_ws, size_t ws_size,
                              hipStream_t stream) {
  const float* pred  = (const float*)d_in[0];
  const float* targ  = (const float*)d_in[1];
  const float* edges = (const float*)d_in[2];
  const void*  mask  = d_in[3];

  char* ws = (char*)d_ws;
  double* sums       = (double*)ws;
  unsigned int* flag = (unsigned int*)(ws + 48);
  float* cs          = (float*)(ws + 64);
  unsigned int* gD   = (unsigned int*)(ws + 8256);

  k_prep<<<NBATCH + 1, NB, 0, stream>>>(edges, (const unsigned char*)mask,
                                        sums, flag, cs, gD);
  k_main<<<MAIN_BLOCKS, NB, 0, stream>>>(pred, targ, mask, flag, cs, sums, gD);
  k_final<<<1, NB, 0, stream>>>(sums, cs, gD, (float*)d_out);
}